// Round 4
// baseline (773.003 us; speedup 1.0000x reference)
//
#include <hip/hip_runtime.h>

#define B_  16384
#define F_  26
#define V_  100000
#define D_  64
#define H1_ 256
#define H2_ 128
#define RPB 16           // batch rows per block (256 thr = 16 rows x 16 lanes)

__device__ __forceinline__ float sigmoidf(float x)
{
    return 1.0f / (1.0f + __expf(-x));
}

// One block = 16 batch rows, 256 threads, fully fused, 4 blocks/CU resident
// (LDS ~22 KB, VGPR capped via __launch_bounds__(256,4)) so the gather phase
// of some blocks overlaps the MLP phase of others on the same CU.
//  P1 gather+FM: thread=(row, 16B col), 26 independent CACHED float4 loads.
//     A/B vs round 3: nt -> normal. Table is 666 MB vs 256 MB L3; allocating
//     loads should give ~38% L3 hits + ~8% duplicate-index hits, reducing
//     the HBM miss count (the binding resource), which nt loads forfeited.
//  P2 GEMM1 fm[16x64]@W1[64x256], thread=column, fm via uniform LDS broadcast
//  P3 GEMM2 h1[16x256]@W2[256x128], wave=(8-row half, 64 cols), butterfly
//  P4 epilogue
__global__ __launch_bounds__(256, 4) void fused_deepfm_kernel(
    const int*   __restrict__ cat,  const float* __restrict__ W2,
    const float* __restrict__ W1,   const float* __restrict__ b1,
    const float* __restrict__ W2w,  const float* __restrict__ b2,
    const float* __restrict__ Wout, const float* __restrict__ bout,
    const float* __restrict__ bias, float* __restrict__ out)
{
    __shared__ int   lidx[RPB][F_];     // 1.7 KB
    __shared__ float fms[RPB][D_];      // 4 KB   (reads are uniform broadcast)
    __shared__ float h1s[RPB][H1_];     // 16 KB
    __shared__ float fmsum[RPB];
    __shared__ float wpart[4][8];

    const int tid  = threadIdx.x;
    const int row0 = blockIdx.x * RPB;

    // ---- stage indices (coalesced) ----
    for (int i = tid; i < RPB * F_; i += 256)
        (&lidx[0][0])[i] = cat[(size_t)row0 * F_ + i];
    __syncthreads();

    // ---------------- P1: gather + FM second-order ----------------
    {
        const int r  = tid >> 4;        // 0..15 local row
        const int d4 = tid & 15;        // 16B column within the 256B row
        const size_t doff = (size_t)(d4 * 4);

        float4 s = {0.f, 0.f, 0.f, 0.f}, q = {0.f, 0.f, 0.f, 0.f};
#pragma unroll
        for (int f = 0; f < F_; ++f) {
            // 16 lanes x 16B = full 256B row; cached load (allocate L2/L3)
            const float4 a = *reinterpret_cast<const float4*>(
                W2 + ((size_t)f * V_ + (size_t)lidx[r][f]) * D_ + doff);
            s.x += a.x; s.y += a.y; s.z += a.z; s.w += a.w;
            q.x += a.x * a.x; q.y += a.y * a.y;
            q.z += a.z * a.z; q.w += a.w * a.w;
        }

        // emb = raw*0.1; fm = 0.5*(s^2 - q) scaled -> 0.005*(s_raw^2 - q_raw)
        float4 g;
        g.x = 0.005f * (s.x * s.x - q.x);
        g.y = 0.005f * (s.y * s.y - q.y);
        g.z = 0.005f * (s.z * s.z - q.z);
        g.w = 0.005f * (s.w * s.w - q.w);
        *reinterpret_cast<float4*>(&fms[r][d4 * 4]) = g;

        // per-row sum over d: reduce across the 16 lanes owning this row
        float p = (g.x + g.y) + (g.z + g.w);
        p += __shfl_xor(p, 1);
        p += __shfl_xor(p, 2);
        p += __shfl_xor(p, 4);
        p += __shfl_xor(p, 8);
        if (d4 == 0) fmsum[r] = p;
    }

    // ---- GEMM1 weight column: issue before barrier, overlaps gather tail ----
    float wc[D_];
#pragma unroll
    for (int d = 0; d < D_; ++d) wc[d] = W1[d * H1_ + tid];   // coalesced, L2
    const float bc = b1[tid];

    __syncthreads();

    // ---------------- P2: GEMM1 + sigmoid -> h1s ----------------
#pragma unroll 4
    for (int r = 0; r < RPB; ++r) {
        float a0 = bc, a1 = 0.f, a2 = 0.f, a3 = 0.f;
#pragma unroll
        for (int d4 = 0; d4 < D_ / 4; ++d4) {
            float4 fv = *reinterpret_cast<const float4*>(&fms[r][d4 * 4]); // broadcast
            a0 += fv.x * wc[d4 * 4 + 0];
            a1 += fv.y * wc[d4 * 4 + 1];
            a2 += fv.z * wc[d4 * 4 + 2];
            a3 += fv.w * wc[d4 * 4 + 3];
        }
        h1s[r][tid] = sigmoidf((a0 + a1) + (a2 + a3));
    }
    __syncthreads();

    // ---------------- P3: GEMM2 + sigmoid*Wout, butterfly reduce ----------------
    {
        const int wid  = tid >> 6;                  // wave 0..3
        const int lane = tid & 63;
        const int c    = ((wid & 1) << 6) + lane;   // h2 column 0..127
        const int rb   = (wid >> 1) * 8;            // rows 0..7 or 8..15

        const float bb = b2[c];
        float acc[8];
#pragma unroll
        for (int r = 0; r < 8; ++r) acc[r] = bb;

        for (int kc = 0; kc < H1_ / 8; ++kc) {
            float wv[8];
#pragma unroll
            for (int j = 0; j < 8; ++j) wv[j] = W2w[(kc * 8 + j) * H2_ + c]; // coalesced
#pragma unroll
            for (int r = 0; r < 8; ++r) {
                const float4* hp = reinterpret_cast<const float4*>(&h1s[rb + r][kc * 8]);
                float4 h0 = hp[0], h4 = hp[1];      // uniform LDS b128 broadcast
                acc[r] += h0.x * wv[0] + h0.y * wv[1] + h0.z * wv[2] + h0.w * wv[3]
                        + h4.x * wv[4] + h4.y * wv[5] + h4.z * wv[6] + h4.w * wv[7];
            }
        }
        const float wo = Wout[c];
#pragma unroll
        for (int r = 0; r < 8; ++r) {
            float v = sigmoidf(acc[r]) * wo;
            v += __shfl_xor(v, 32);
            v += __shfl_xor(v, 16);
            v += __shfl_xor(v, 8);
            v += __shfl_xor(v, 4);
            v += __shfl_xor(v, 2);
            v += __shfl_xor(v, 1);
            if (lane == 0) wpart[wid][r] = v;
        }
    }
    __syncthreads();

    // ---------------- P4: final sum ----------------
    if (tid < RPB) {
        const int hh = tid >> 3;            // 0: rows 0-7, 1: rows 8-15
        const int r  = tid & 7;
        out[row0 + tid] = wpart[2 * hh][r] + wpart[2 * hh + 1][r]
                        + bout[0] + bias[0] + fmsum[tid];
    }
}

extern "C" void kernel_launch(void* const* d_in, const int* in_sizes, int n_in,
                              void* d_out, int out_size, void* d_ws, size_t ws_size,
                              hipStream_t stream)
{
    const int*   cat  = (const int*)  d_in[0];
    const float* W2   = (const float*)d_in[1];
    const float* W1   = (const float*)d_in[2];
    const float* b1   = (const float*)d_in[3];
    const float* W2w  = (const float*)d_in[4];
    const float* b2   = (const float*)d_in[5];
    const float* Wout = (const float*)d_in[6];
    const float* bout = (const float*)d_in[7];
    const float* bias = (const float*)d_in[8];
    float* out = (float*)d_out;

    fused_deepfm_kernel<<<B_ / RPB, 256, 0, stream>>>(
        cat, W2, W1, b1, W2w, b2, Wout, bout, bias, out);
}